// Round 13
// baseline (163.785 us; speedup 1.0000x reference)
//
#include <hip/hip_runtime.h>
#include <math.h>

// Problem constants (from reference setup_inputs)
#define B 64
#define N 128            // logits H=W
#define M 136            // targets H=W
#define S2 9             // shift cols (and rows)
#define S 81
#define NPIX (N*N)       // 16384
#define MPIX (M*M)       // 18496
#define CENTER 40        // 4*9 + 4
#define STRIPS 16        // row strips per batch
#define SROWS 8          // x rows per strip
#define YR 16            // y rows staged per strip (8 + 8 window)
#define YF4S 544         // float4 staged per strip (16*34)

// R13: single dispatch. R12 probe: k_corr + dispatch-gap = 8.4 us -> boundary
// overhead ~5 us dominates the controllable budget. This kernel = R10 phase 1
// (byte-identical math) + capped sibling-wait + R10 k_out's phase 2 run by ALL
// 1024 blocks (full parallelism, unlike R11's 64-block serial finisher).

// Fast softplus for the shift-independent BCE term: max(x,0)+log1p(exp(-|x|)).
// This term does NOT affect the argmin (argmin_s(P - D_s) == argmax_s D_s).
__device__ __forceinline__ float softplus_f(float x) {
    float t = __expf(-fabsf(x));
    return fmaxf(x, 0.0f) + __logf(1.0f + t);
}

// VALU-pipe cross-lane add: x + (x rotated right by n within each 16-lane row).
// After ctrl 0x128,0x124,0x122,0x121 every lane holds its row-of-16 sum.
#define ROR_ADD(x, CTRL) ((x) + __int_as_float(__builtin_amdgcn_update_dpp( \
        0, __float_as_int(x), (CTRL), 0xf, 0xf, true)))

// ---------------- Single kernel: strip corr + capped-wait + parallel finish --
// grid = 1024 blocks (b = bid&63, st = bid>>6 -> all 16 siblings of a batch on
// one XCD since 64%8==0; D2/P2 stay in one L2), 256 threads, ~14.2 KB LDS,
// <=128 VGPR -> 4 blocks/CU; grid fits device capacity 2x over.
// Sync protocol (deadlock-free by construction):
//   - counter = out row_shifts slot (harness zeroes out before each launch;
//     protocol proven in R11). Release fence + device-scope atomicAdd(1).
//   - non-last blocks poll with device-scope acquire loads, CAPPED at 6000
//     polls (~0.3 ms) -> no infinite spin possible. On cap-exhaust: proceed
//     (siblings are physically done microseconds earlier; D2 complete).
//   - phase 2 is SELF-SUFFICIENT per block: fixed-order strip sum + argmax
//     recomputed from D2 (bit-identical everywhere), so no block depends on
//     another block's phase-2 writes. st==0 writes shifts (overwriting the
//     counter) + loss LAST, after its gather, maximizing the spin margin.
__global__ __launch_bounds__(256, 4) void k_one(const float* __restrict__ x,
                                                const float* __restrict__ y,
                                                float* __restrict__ D2,
                                                float* __restrict__ P2,
                                                float* __restrict__ out) {
    const int tid = threadIdx.x;
    const int b  = blockIdx.x & 63;     // batch
    const int st = blockIdx.x >> 6;     // strip 0..15 (same XCD for fixed b)

    __shared__ float ylds[YR * M];      // 8704 B: y rows [st*8, st*8+16)
    __shared__ float part[16][81];      // 5184 B
    __shared__ float spart[4];
    __shared__ float dsum[S];
    __shared__ float sbv;
    __shared__ int sij;

    const int lr = tid >> 5;            // strip-local x row 0..7
    const int cq = tid & 31;            // column quad 0..31

    // x quad for this thread (read once, global/L2)
    const float4 xv = ((const float4*)(x + (size_t)b * NPIX
                                         + (st * SROWS + lr) * N))[cq];

    // stage y rows [st*8, st*8+16): 544 float4, coalesced
    {
        const float4* ysrc = (const float4*)(y + (size_t)b * MPIX + st * SROWS * M);
        float4* ydst = (float4*)ylds;
        #pragma unroll
        for (int t = 0; t < 3; ++t) {
            int idx = tid + 256 * t;
            if (idx < YF4S) ydst[idx] = ysrc[idx];
        }
    }

    // softplus partial over this thread's 4 x values (block covers strip once)
    float sp = softplus_f(xv.x) + softplus_f(xv.y)
             + softplus_f(xv.z) + softplus_f(xv.w);

    __syncthreads();

    const int g = tid >> 4;             // 16-lane group id 0..15
    const bool lead = (tid & 15) == 0;

    // 9 shift rows; per row: 3 ds_read_b128, 36 FMA, 36 DPP-adds, 9 LDS flush.
    // Low register pressure (R10): no acc[81], ~40 live VGPRs, no spill.
    #pragma unroll
    for (int ii = 0; ii < 9; ++ii) {
        const float* yrow = ylds + (lr + ii) * M + cq * 4;   // rows 0..15
        float4 A  = *(const float4*)(yrow);
        float4 Bq = *(const float4*)(yrow + 4);
        float4 Cq = *(const float4*)(yrow + 8);
        float ya[12];
        ya[0] = A.x;  ya[1] = A.y;  ya[2] = A.z;  ya[3] = A.w;
        ya[4] = Bq.x; ya[5] = Bq.y; ya[6] = Bq.z; ya[7] = Bq.w;
        ya[8] = Cq.x; ya[9] = Cq.y; ya[10] = Cq.z; ya[11] = Cq.w;
        #pragma unroll
        for (int j = 0; j < 9; ++j) {
            float v = xv.x * ya[j]     + xv.y * ya[j + 1]
                    + xv.z * ya[j + 2] + xv.w * ya[j + 3];
            v = ROR_ADD(v, 0x128);   // +ror16:8
            v = ROR_ADD(v, 0x124);   // +ror16:4
            v = ROR_ADD(v, 0x122);   // +ror16:2
            v = ROR_ADD(v, 0x121);   // +ror16:1  -> 16-lane sum in every lane
            if (lead) part[g][ii * 9 + j] = v;
        }
    }

    #pragma unroll
    for (int m = 1; m < 64; m <<= 1) sp += __shfl_xor(sp, m, 64);
    if ((tid & 63) == 0) spart[tid >> 6] = sp;
    __syncthreads();

    if (tid < S) {
        float s0 = 0.0f;
        #pragma unroll
        for (int gg = 0; gg < 16; ++gg) s0 += part[gg][tid];   // fixed order
        D2[((size_t)b * STRIPS + st) * S + tid] = s0;
    }
    if (tid == 96) {
        P2[b * STRIPS + st] = (spart[0] + spart[1]) + (spart[2] + spart[3]);
    }

    // ---- sibling-completion protocol (counter in out row_shifts slot) ------
    __syncthreads();                     // all D2/P2 stores issued
    {
        float* cnt = out + 1 + (size_t)B * NPIX + b;
        if (tid == 0) {
            __threadfence();             // release: D2/P2 device-visible
            float old = atomicAdd(cnt, 1.0f);
            if (old < 15.0f) {           // not last: capped poll
                int it = 0;
                while (it < 6000) {
                    float v = __hip_atomic_load(cnt, __ATOMIC_ACQUIRE,
                                                __HIP_MEMORY_SCOPE_AGENT);
                    if (v >= 16.0f) break;
                    __builtin_amdgcn_s_sleep(2);
                    ++it;
                }
                // cap-exhaust: proceed anyway (see header comment)
            }
        }
        __syncthreads();
        __threadfence();                 // acquire: see siblings' D2/P2
    }

    // ---- phase 2 (every block, self-sufficient, bit-identical) -------------
    if (tid < S) {
        float s0 = 0.0f;
        #pragma unroll
        for (int ss = 0; ss < STRIPS; ++ss)              // fixed order
            s0 += D2[((size_t)b * STRIPS + ss) * S + tid];
        dsum[tid] = s0;
    }
    __syncthreads();

    // wave-parallel argmax over 81 (first-index tiebreak, then center)
    if (tid < 64) {
        float bv = dsum[tid];
        int   bi = tid;
        if (tid < S - 64) {                              // fold entries 64..80
            float v2 = dsum[64 + tid];
            if (v2 > bv) { bv = v2; bi = 64 + tid; }     // larger idx: strict >
        }
        #pragma unroll
        for (int m = 1; m < 64; m <<= 1) {
            float ov = __shfl_xor(bv, m, 64);
            int   oi = __shfl_xor(bi, m, 64);
            if (ov > bv || (ov == bv && oi < bi)) { bv = ov; bi = oi; }
        }
        if (tid == 0) {
            if (dsum[CENTER] == bv) bi = CENTER;         // center tiebreak
            sij = bi;
            sbv = bv;
        }
    }
    __syncthreads();

    // gather: this block's st-slice, 1 output quad per thread (disjoint)
    {
        const int ij = sij;
        const int i2 = ij / S2, j2 = ij - i2 * S2;
        const int Q = st * 256 + tid;                    // batch quad 0..4095
        const int row = (Q >> 5) + i2;                   // y row <= 135
        const float* yrow = y + (size_t)b * MPIX + row * M + (Q & 31) * 4 + j2;
        float* d = out + 1 + (size_t)b * NPIX + 4 * Q;
        d[0] = yrow[0]; d[1] = yrow[1]; d[2] = yrow[2]; d[3] = yrow[3];
    }

    // scalar outputs LAST (st==0): overwrites the counter slot well after all
    // siblings passed the spin; cap-bailout covers the pathological miss.
    if (st == 0 && tid == 0) {
        const int bi = sij;
        out[1 + B * NPIX + b]     = (float)(bi / S2);    // row_shifts
        out[1 + B * NPIX + B + b] = (float)(bi % S2);    // col_shifts
        float P = 0.0f;
        #pragma unroll
        for (int ss = 0; ss < STRIPS; ++ss) P += P2[b * STRIPS + ss];
        // per-batch min_loss term; out[0] zeroed by harness before launch
        atomicAdd(out, (P - sbv) * (1.0f / (float)NPIX));
    }
}

extern "C" void kernel_launch(void* const* d_in, const int* in_sizes, int n_in,
                              void* d_out, int out_size, void* d_ws, size_t ws_size,
                              hipStream_t stream) {
    const float* x = (const float*)d_in[0];   // logits (64,1,128,128)
    const float* y = (const float*)d_in[1];   // targets (64,1,136,136)
    float* out = (float*)d_out;               // [1 + 64*16384 + 64 + 64]

    float* wsF = (float*)d_ws;
    float* D2  = wsF;                         // 64*16*81 floats
    float* P2  = wsF + B * STRIPS * S;        // 64*16 floats

    k_one<<<dim3(B * STRIPS), 256, 0, stream>>>(x, y, D2, P2, out);
}

// Round 14
// 73.867 us; speedup vs baseline: 2.2173x; 2.2173x over previous
//
#include <hip/hip_runtime.h>
#include <math.h>

// Problem constants (from reference setup_inputs)
#define B 64
#define N 128            // logits H=W
#define M 136            // targets H=W
#define S2 9             // shift cols (and rows)
#define S 81
#define NPIX (N*N)       // 16384
#define MPIX (M*M)       // 18496
#define CENTER 40        // 4*9 + 4
#define STRIPS 16        // row strips per batch
#define SROWS 8          // x rows per strip
#define YR 16            // y rows staged per strip (8 + 8 window)
#define YF4S 544         // float4 staged per strip (16*34)

// R14 = R10 with the producer/consumer XCD alignment fixed:
//   - both kernels decode b = bid&63, st/p = bid>>6 -> all 16 strip-writers
//     AND all 16 output-readers of batch b sit on XCD b%8; D2, P2 and y[b]
//     stay in ONE L2 (R10's b*16+st decode scattered strips across all XCDs,
//     making ~14/16 of k_out's D2 reads remote).
//   - k_out stages D2[b] cooperatively into LDS (coalesced, all 256 threads)
//     and gathers with float4 loads (R10's gather2 trick).
// All FP orders unchanged -> D2/dsum/argmax bit-identical to R10.

// Fast softplus for the shift-independent BCE term: max(x,0)+log1p(exp(-|x|)).
// This term does NOT affect the argmin (argmin_s(P - D_s) == argmax_s D_s).
__device__ __forceinline__ float softplus_f(float x) {
    float t = __expf(-fabsf(x));
    return fmaxf(x, 0.0f) + __logf(1.0f + t);
}

// VALU-pipe cross-lane add: x + (x rotated right by n within each 16-lane row).
// After ctrl 0x128,0x124,0x122,0x121 every lane holds its row-of-16 sum.
#define ROR_ADD(x, CTRL) ((x) + __int_as_float(__builtin_amdgcn_update_dpp( \
        0, __float_as_int(x), (CTRL), 0xf, 0xf, true)))

// ---------------- Kernel 1: strip correlation partials (no redundancy) -------
// grid = 1024 blocks (b = bid&63, st = bid>>6), 256 threads, ~14.2 KB LDS,
// low VGPR (R10 fix: per-shift-row reduce+flush, no acc[81]) -> 4 blocks/CU.
__global__ __launch_bounds__(256, 4) void k_corr(const float* __restrict__ x,
                                                 const float* __restrict__ y,
                                                 float* __restrict__ D2,
                                                 float* __restrict__ P2) {
    const int tid = threadIdx.x;
    const int b  = blockIdx.x & 63;     // batch
    const int st = blockIdx.x >> 6;     // strip 0..15 (same XCD for fixed b)

    __shared__ float ylds[YR * M];      // 8704 B: y rows [st*8, st*8+16)
    __shared__ float part[16][81];      // 5184 B
    __shared__ float spart[4];

    const int lr = tid >> 5;            // strip-local x row 0..7
    const int cq = tid & 31;            // column quad 0..31

    // x quad for this thread (read once, global/L2)
    const float4 xv = ((const float4*)(x + (size_t)b * NPIX
                                         + (st * SROWS + lr) * N))[cq];

    // stage y rows [st*8, st*8+16): 544 float4, coalesced
    {
        const float4* ysrc = (const float4*)(y + (size_t)b * MPIX + st * SROWS * M);
        float4* ydst = (float4*)ylds;
        #pragma unroll
        for (int t = 0; t < 3; ++t) {
            int idx = tid + 256 * t;
            if (idx < YF4S) ydst[idx] = ysrc[idx];
        }
    }

    // softplus partial over this thread's 4 x values (block covers strip once)
    float sp = softplus_f(xv.x) + softplus_f(xv.y)
             + softplus_f(xv.z) + softplus_f(xv.w);

    __syncthreads();

    const int g = tid >> 4;             // 16-lane group id 0..15
    const bool lead = (tid & 15) == 0;

    // 9 shift rows; per row: 3 ds_read_b128, 36 FMA, 36 DPP-adds, 9 LDS flush
    #pragma unroll
    for (int ii = 0; ii < 9; ++ii) {
        const float* yrow = ylds + (lr + ii) * M + cq * 4;   // rows 0..15
        float4 A  = *(const float4*)(yrow);
        float4 Bq = *(const float4*)(yrow + 4);
        float4 Cq = *(const float4*)(yrow + 8);
        float ya[12];
        ya[0] = A.x;  ya[1] = A.y;  ya[2] = A.z;  ya[3] = A.w;
        ya[4] = Bq.x; ya[5] = Bq.y; ya[6] = Bq.z; ya[7] = Bq.w;
        ya[8] = Cq.x; ya[9] = Cq.y; ya[10] = Cq.z; ya[11] = Cq.w;
        #pragma unroll
        for (int j = 0; j < 9; ++j) {
            float v = xv.x * ya[j]     + xv.y * ya[j + 1]
                    + xv.z * ya[j + 2] + xv.w * ya[j + 3];
            v = ROR_ADD(v, 0x128);   // +ror16:8
            v = ROR_ADD(v, 0x124);   // +ror16:4
            v = ROR_ADD(v, 0x122);   // +ror16:2
            v = ROR_ADD(v, 0x121);   // +ror16:1  -> 16-lane sum in every lane
            if (lead) part[g][ii * 9 + j] = v;
        }
    }

    #pragma unroll
    for (int m = 1; m < 64; m <<= 1) sp += __shfl_xor(sp, m, 64);
    if ((tid & 63) == 0) spart[tid >> 6] = sp;
    __syncthreads();

    if (tid < S) {
        float s0 = 0.0f;
        #pragma unroll
        for (int gg = 0; gg < 16; ++gg) s0 += part[gg][tid];   // fixed order
        D2[((size_t)b * STRIPS + st) * S + tid] = s0;
    }
    if (tid == 96) {
        P2[b * STRIPS + st] = (spart[0] + spart[1]) + (spart[2] + spart[3]);
    }
}

// ---------------- Kernel 2: argmax + gather + scalar outputs ----------------
// grid = 1024 blocks (b = bid&63, p = bid>>6 -> same XCD as batch b's
// k_corr writers), 256 threads. All blocks of a batch compute the same
// fixed-order strip sum + argmax (bit-identical; no communication). Block p
// gathers batch quads [p*256, (p+1)*256) from global y (home-L2 resident).
template <int O>
__device__ __forceinline__ void gatherq(const float* __restrict__ y, float* d,
                                        int b, int Q, int i2, int j2) {
    const float4* yl4 = (const float4*)(y + (size_t)b * MPIX);
    const int row = (Q >> 5) + i2;                 // y row <= 135
    const int i0 = (Q & 31) + (j2 >> 2);           // aligned f4 col (<= 33)
    const int rb = row * (M / 4);
    float4 A = yl4[rb + i0];
    float r0, r1, r2, r3;
    if (O == 0) { r0 = A.x; r1 = A.y; r2 = A.z; r3 = A.w; }
    else {
        float4 Bq = yl4[rb + i0 + 1];              // O!=0 -> i0+1 <= 33
        if (O == 1)      { r0 = A.y; r1 = A.z; r2 = A.w; r3 = Bq.x; }
        else if (O == 2) { r0 = A.z; r1 = A.w; r2 = Bq.x; r3 = Bq.y; }
        else             { r0 = A.w; r1 = Bq.x; r2 = Bq.y; r3 = Bq.z; }
    }
    d[0] = r0; d[1] = r1; d[2] = r2; d[3] = r3;    // out+1 unaligned: scalars
}

__global__ __launch_bounds__(256) void k_out(const float* __restrict__ y,
                                             const float* __restrict__ D2,
                                             const float* __restrict__ P2,
                                             float* __restrict__ out) {
    const int tid = threadIdx.x;
    const int b = blockIdx.x & 63;      // batch (same XCD as its writers)
    const int p = blockIdx.x >> 6;      // output slice 0..15

    __shared__ float dlds[STRIPS * S];  // 1296 floats: D2[b], staged coalesced
    __shared__ float dsum[S];
    __shared__ int sij;

    // cooperative, coalesced staging of all 16 strips' partials
    {
        const float* src = D2 + (size_t)b * STRIPS * S;
        #pragma unroll
        for (int t = 0; t < 6; ++t) {
            int idx = tid + 256 * t;
            if (idx < STRIPS * S) dlds[idx] = src[idx];
        }
    }
    __syncthreads();

    if (tid < S) {
        float s0 = 0.0f;
        #pragma unroll
        for (int st = 0; st < STRIPS; ++st)          // fixed order (as R10)
            s0 += dlds[st * S + tid];
        dsum[tid] = s0;
    }
    __syncthreads();

    // wave-parallel argmax over 81 (first-index tiebreak, then center)
    if (tid < 64) {
        float bv = dsum[tid];
        int   bi = tid;
        if (tid < S - 64) {                          // fold entries 64..80
            float v2 = dsum[64 + tid];
            if (v2 > bv) { bv = v2; bi = 64 + tid; } // larger idx: strict >
        }
        #pragma unroll
        for (int m = 1; m < 64; m <<= 1) {
            float ov = __shfl_xor(bv, m, 64);
            int   oi = __shfl_xor(bi, m, 64);
            if (ov > bv || (ov == bv && oi < bi)) { bv = ov; bi = oi; }
        }
        if (tid == 0) {
            if (dsum[CENTER] == bv) bi = CENTER;     // center tiebreak
            sij = bi;
            if (p == 0) {
                out[1 + B * NPIX + b]     = (float)(bi / S2);   // row_shifts
                out[1 + B * NPIX + B + b] = (float)(bi % S2);   // col_shifts
                float P = 0.0f;
                #pragma unroll
                for (int st = 0; st < STRIPS; ++st) P += P2[b * STRIPS + st];
                // per-batch min_loss; out[0] zeroed by harness before launch
                atomicAdd(out, (P - bv) * (1.0f / (float)NPIX));
            }
        }
    }
    __syncthreads();

    // gather: 1 output quad per thread via float4 loads (offset-select)
    {
        const int ij = sij;
        const int i2 = ij / S2, j2 = ij - i2 * S2;
        const int Q = p * 256 + tid;                 // batch quad 0..4095
        float* d = out + 1 + (size_t)b * NPIX + 4 * Q;
        const int o = j2 & 3;                        // block-uniform branch
        if (o == 0)      gatherq<0>(y, d, b, Q, i2, j2);
        else if (o == 1) gatherq<1>(y, d, b, Q, i2, j2);
        else if (o == 2) gatherq<2>(y, d, b, Q, i2, j2);
        else             gatherq<3>(y, d, b, Q, i2, j2);
    }
}

extern "C" void kernel_launch(void* const* d_in, const int* in_sizes, int n_in,
                              void* d_out, int out_size, void* d_ws, size_t ws_size,
                              hipStream_t stream) {
    const float* x = (const float*)d_in[0];   // logits (64,1,128,128)
    const float* y = (const float*)d_in[1];   // targets (64,1,136,136)
    float* out = (float*)d_out;               // [1 + 64*16384 + 64 + 64]

    float* wsF = (float*)d_ws;
    float* D2  = wsF;                         // 64*16*81 floats
    float* P2  = wsF + B * STRIPS * S;        // 64*16 floats

    k_corr<<<dim3(B * STRIPS), 256, 0, stream>>>(x, y, D2, P2);
    k_out<<<dim3(B * STRIPS), 256, 0, stream>>>(y, D2, P2, out);
}